// Round 4
// baseline (291.244 us; speedup 1.0000x reference)
//
#include <hip/hip_runtime.h>
#include <math.h>

#define NB 32
#define NS 4096
#define ND 160
#define ND4 40              // ND in float4
#define NM 16
#define NR 16
#define TPB 128             // tokens per block
#define NCB (NS / TPB)      // 32 chunks per batch

// ---------------------------------------------------------------------------
// Kernel 0: fold weights per batch:
//   K[m][d] = 0.25 * sum_r mem16[m][r] * Wrk[r][d]
//   V[m][d] =        sum_r mem16[m][r] * Wrv[d][r]
// kvbuf layout: [NB][2][NM][ND]  (K plane then V plane)
// grid = NB, block = 256
// ---------------------------------------------------------------------------
__global__ __launch_bounds__(256) void ulm_fold_kv(
    const float* __restrict__ memory,
    const float* __restrict__ Wrk,     // [NR][ND]
    const float* __restrict__ Wrv,     // [ND][NR]
    float* __restrict__ kvbuf)
{
    __shared__ float sM16[NM * NR];
    const int b = blockIdx.x;
    const int t = threadIdx.x;
    {
        int m = t >> 4, r = t & 15;
        sM16[t] = memory[((size_t)b * NM + m) * ND + r];
    }
    __syncthreads();
    if (t < ND) {
        float wk[NR], wv[NR];
#pragma unroll
        for (int r = 0; r < NR; ++r) wk[r] = Wrk[r * ND + t];
        const float4* wrv4 = reinterpret_cast<const float4*>(Wrv + t * NR);
#pragma unroll
        for (int j = 0; j < 4; ++j) {
            float4 v = wrv4[j];
            wv[j * 4 + 0] = v.x; wv[j * 4 + 1] = v.y;
            wv[j * 4 + 2] = v.z; wv[j * 4 + 3] = v.w;
        }
        float* kb = kvbuf + (size_t)b * 2 * NM * ND;
#pragma unroll
        for (int m = 0; m < NM; ++m) {
            float aK = 0.f, aV = 0.f;
#pragma unroll
            for (int r = 0; r < NR; ++r) {
                float mv = sM16[m * NR + r];
                aK += mv * wk[r];
                aV += mv * wv[r];
            }
            kb[m * ND + t]           = aK * 0.25f;   // fold 1/sqrt(R)
            kb[NM * ND + m * ND + t] = aV;
        }
    }
}

// ---------------------------------------------------------------------------
// Kernel 1: read path. scores = q·K^T, softmax, out = attn·V.
// Fused: partial column-sums of `interface` -> ipart.
// grid = (NCB, NB), block = 256. 8 lanes per group, 4 tokens per group.
// ---------------------------------------------------------------------------
__global__ __launch_bounds__(256, 4) void ulm_read_kernel(
    const float* __restrict__ query,
    const float* __restrict__ iface,
    const float* __restrict__ kvbuf,   // [NB][2][NM][ND]
    float* __restrict__ read_out,      // [NB][NS][ND]
    float* __restrict__ ipart)         // [NB][NCB][ND]
{
    __shared__ __align__(16) float sKV[2 * NM * ND];  // 20 KB: K then V
    __shared__ float4 sIred[4 * ND4];                 // 2.5 KB

    const int t = threadIdx.x;
    const int chunk = blockIdx.x;
    const int b = blockIdx.y;
    const int s0 = chunk * TPB;

    // --- stage folded K,V (coalesced, conflict-free) ------------------------
    {
        const float4* kv4 = reinterpret_cast<const float4*>(kvbuf + (size_t)b * 2 * NM * ND);
        float4* s4 = reinterpret_cast<float4*>(sKV);
#pragma unroll
        for (int j = 0; j < 5; ++j) s4[j * 256 + t] = kv4[j * 256 + t];
    }
    __syncthreads();

    const float4* sK4 = reinterpret_cast<const float4*>(sKV);
    const float4* sV4 = sK4 + NM * ND4;

    const int l = t & 7;                  // lane in 8-lane group
    const int G = t >> 3;                 // group 0..31
    const int tokb = G * 4;               // 4 tokens per group

    const float4* q4 = reinterpret_cast<const float4*>(query + ((size_t)b * NS + s0) * ND);

    // --- scores: 16 dots of length 160 per token, 8-lane distributed -------
    float sc[4][NM];
#pragma unroll
    for (int i = 0; i < 4; ++i)
#pragma unroll
        for (int m = 0; m < NM; ++m) sc[i][m] = 0.f;

#pragma unroll
    for (int k = 0; k < 5; ++k) {
        float4 qa[4];
#pragma unroll
        for (int i = 0; i < 4; ++i) qa[i] = q4[(tokb + i) * ND4 + l + 8 * k];
#pragma unroll
        for (int m = 0; m < NM; ++m) {
            float4 kv = sK4[m * ND4 + l + 8 * k];
#pragma unroll
            for (int i = 0; i < 4; ++i)
                sc[i][m] += qa[i].x * kv.x + qa[i].y * kv.y
                          + qa[i].z * kv.z + qa[i].w * kv.w;
        }
    }
#pragma unroll
    for (int i = 0; i < 4; ++i)
#pragma unroll
        for (int m = 0; m < NM; ++m) {
            float v = sc[i][m];
            v += __shfl_xor(v, 1);
            v += __shfl_xor(v, 2);
            v += __shfl_xor(v, 4);
            sc[i][m] = v;
        }

    // --- softmax (redundant per lane) ---------------------------------------
#pragma unroll
    for (int i = 0; i < 4; ++i) {
        float mx = -1e30f;
#pragma unroll
        for (int m = 0; m < NM; ++m) mx = fmaxf(mx, sc[i][m]);
        float sm = 0.f;
#pragma unroll
        for (int m = 0; m < NM; ++m) { float e = __expf(sc[i][m] - mx); sc[i][m] = e; sm += e; }
        float inv = 1.f / sm;
#pragma unroll
        for (int m = 0; m < NM; ++m) sc[i][m] *= inv;
    }

    // --- iface loads + register accumulation (PV below hides latency) ------
    const float4* i4 = reinterpret_cast<const float4*>(iface + ((size_t)b * NS + s0) * ND);
    float4 ia[5];
#pragma unroll
    for (int k = 0; k < 5; ++k) ia[k] = make_float4(0.f, 0.f, 0.f, 0.f);
#pragma unroll
    for (int i = 0; i < 4; ++i)
#pragma unroll
        for (int k = 0; k < 5; ++k) {
            float4 v = i4[(tokb + i) * ND4 + l + 8 * k];
            ia[k].x += v.x; ia[k].y += v.y; ia[k].z += v.z; ia[k].w += v.w;
        }

    // --- out = attn · V ------------------------------------------------------
    float4* out4 = reinterpret_cast<float4*>(read_out + ((size_t)b * NS + s0) * ND);
#pragma unroll
    for (int k = 0; k < 5; ++k) {
        float4 o[4];
#pragma unroll
        for (int i = 0; i < 4; ++i) o[i] = make_float4(0.f, 0.f, 0.f, 0.f);
#pragma unroll
        for (int m = 0; m < NM; ++m) {
            float4 vv = sV4[m * ND4 + l + 8 * k];
#pragma unroll
            for (int i = 0; i < 4; ++i) {
                o[i].x += sc[i][m] * vv.x; o[i].y += sc[i][m] * vv.y;
                o[i].z += sc[i][m] * vv.z; o[i].w += sc[i][m] * vv.w;
            }
        }
#pragma unroll
        for (int i = 0; i < 4; ++i)
            out4[(tokb + i) * ND4 + l + 8 * k] = o[i];
    }

    // --- iface: single butterfly across the 8 groups of each wave ----------
    const int w = t >> 6;
#pragma unroll
    for (int k = 0; k < 5; ++k) {
        float x = ia[k].x, y = ia[k].y, z = ia[k].z, u = ia[k].w;
#pragma unroll
        for (int off = 8; off <= 32; off <<= 1) {
            x += __shfl_xor(x, off); y += __shfl_xor(y, off);
            z += __shfl_xor(z, off); u += __shfl_xor(u, off);
        }
        if ((t & 63) < 8) sIred[w * ND4 + k * 8 + l] = make_float4(x, y, z, u);
    }
    __syncthreads();
    if (t < ND4) {
        float4 a0 = sIred[t], a1 = sIred[ND4 + t];
        float4 a2 = sIred[2 * ND4 + t], a3 = sIred[3 * ND4 + t];
        float4 tot = make_float4(a0.x + a1.x + a2.x + a3.x,
                                 a0.y + a1.y + a2.y + a3.y,
                                 a0.z + a1.z + a2.z + a3.z,
                                 a0.w + a1.w + a2.w + a3.w);
        reinterpret_cast<float4*>(ipart + ((size_t)(b * NCB + chunk)) * ND)[t] = tot;
    }
}

// ---------------------------------------------------------------------------
// Kernel 2: write path. i_mean -> i_proj -> erase/add -> layer_norm(new_mem)
// grid = NB, block = 256
// ---------------------------------------------------------------------------
__global__ __launch_bounds__(256) void ulm_write_kernel(
    const float* __restrict__ memory,
    const float* __restrict__ Wwk,     // [NR][ND]
    const float* __restrict__ Wwe,     // [ND][NR]
    const float* __restrict__ Wwa,     // [ND][NR]
    const float* __restrict__ ipart,   // [NB][NCB][ND]
    float* __restrict__ new_mem)       // [NB][NM][ND]
{
    __shared__ float sIm[ND];
    __shared__ float sIp[NR];
    __shared__ float sOmE[ND];   // 1 - erase
    __shared__ float sAdd[ND];

    const int b = blockIdx.x;
    const int t = threadIdx.x;

    if (t < ND) {
        float acc = 0.f;
#pragma unroll 8
        for (int c = 0; c < NCB; ++c)
            acc += ipart[((size_t)(b * NCB + c)) * ND + t];
        sIm[t] = acc * (1.0f / NS);
    }
    __syncthreads();

    if (t < NR) {
        float acc = 0.f;
        for (int d = 0; d < ND; ++d) acc += sIm[d] * Wwk[t * ND + d];
        sIp[t] = acc;
    }
    __syncthreads();

    if (t < ND) {
        float e = 0.f, a = 0.f;
#pragma unroll
        for (int r = 0; r < NR; ++r) {
            float ip = sIp[r];
            e += ip * Wwe[t * NR + r];
            a += ip * Wwa[t * NR + r];
        }
        sOmE[t] = 1.0f - 1.0f / (1.0f + __expf(-e));
        sAdd[t] = a;
    }
    __syncthreads();

    // layer norm each of the 16 memory rows; one wave per row
    const int wave = t >> 6, lane = t & 63;
    for (int m = wave; m < NM; m += 4) {
        const float* mrow = memory + ((size_t)b * NM + m) * ND;
        float v0 = mrow[lane] * sOmE[lane] + sAdd[lane];
        float v1 = mrow[lane + 64] * sOmE[lane + 64] + sAdd[lane + 64];
        float v2 = 0.f;
        const bool has2 = lane < 32;
        if (has2) v2 = mrow[lane + 128] * sOmE[lane + 128] + sAdd[lane + 128];
        float s  = v0 + v1 + v2;
        float sq = v0 * v0 + v1 * v1 + v2 * v2;
#pragma unroll
        for (int off = 32; off; off >>= 1) {
            s  += __shfl_xor(s, off);
            sq += __shfl_xor(sq, off);
        }
        float mu   = s * (1.0f / ND);
        float var  = sq * (1.0f / ND) - mu * mu;
        float rstd = rsqrtf(var + 1e-5f);
        float* orow = new_mem + ((size_t)b * NM + m) * ND;
        orow[lane]      = (v0 - mu) * rstd;
        orow[lane + 64] = (v1 - mu) * rstd;
        if (has2) orow[lane + 128] = (v2 - mu) * rstd;
    }
}

extern "C" void kernel_launch(void* const* d_in, const int* in_sizes, int n_in,
                              void* d_out, int out_size, void* d_ws, size_t ws_size,
                              hipStream_t stream) {
    const float* query  = (const float*)d_in[0];
    const float* iface  = (const float*)d_in[1];
    const float* memory = (const float*)d_in[2];
    const float* Wrk    = (const float*)d_in[3];
    const float* Wrv    = (const float*)d_in[4];
    const float* Wwk    = (const float*)d_in[5];
    const float* Wwe    = (const float*)d_in[6];
    const float* Wwa    = (const float*)d_in[7];

    float* read_out = (float*)d_out;                        // [32][4096][160]
    float* new_mem  = (float*)d_out + (size_t)NB * NS * ND; // [32][16][160]
    float* ipart    = (float*)d_ws;                         // NB*NCB*ND f32 = 655 KB
    float* kvbuf    = (float*)d_ws + (size_t)NB * NCB * ND; // NB*2*NM*ND f32 = 655 KB

    ulm_fold_kv<<<NB, 256, 0, stream>>>(memory, Wrk, Wrv, kvbuf);
    dim3 grid1(NCB, NB);
    ulm_read_kernel<<<grid1, 256, 0, stream>>>(query, iface, kvbuf,
                                               read_out, ipart);
    ulm_write_kernel<<<NB, 256, 0, stream>>>(memory, Wwk, Wwe, Wwa, ipart, new_mem);
}

// Round 5
// 82.495 us; speedup vs baseline: 3.5305x; 3.5305x over previous
//
#include <hip/hip_runtime.h>
#include <math.h>

#define NB 32
#define NS 4096
#define ND 160
#define ND4 40              // ND in float4
#define NM 16
#define NR 16
#define TPB 128             // tokens per block
#define NCB (NS / TPB)      // 32 chunks per batch

typedef float f32x4 __attribute__((ext_vector_type(4)));

// ---------------------------------------------------------------------------
// Kernel 0: fold weights per batch:
//   K[m][d] = 0.25 * sum_r mem16[m][r] * Wrk[r][d]
//   V[m][d] =        sum_r mem16[m][r] * Wrv[d][r]
// kvbuf layout: [NB][2][NM][ND]  (K plane then V plane)
// grid = NB, block = 256
// ---------------------------------------------------------------------------
__global__ __launch_bounds__(256) void ulm_fold_kv(
    const float* __restrict__ memory,
    const float* __restrict__ Wrk,     // [NR][ND]
    const float* __restrict__ Wrv,     // [ND][NR]
    float* __restrict__ kvbuf)
{
    __shared__ float sM16[NM * NR];
    const int b = blockIdx.x;
    const int t = threadIdx.x;
    {
        int m = t >> 4, r = t & 15;
        sM16[t] = memory[((size_t)b * NM + m) * ND + r];
    }
    __syncthreads();
    if (t < ND) {
        float wk[NR], wv[NR];
#pragma unroll
        for (int r = 0; r < NR; ++r) wk[r] = Wrk[r * ND + t];
        const float4* wrv4 = reinterpret_cast<const float4*>(Wrv + t * NR);
#pragma unroll
        for (int j = 0; j < 4; ++j) {
            float4 v = wrv4[j];
            wv[j * 4 + 0] = v.x; wv[j * 4 + 1] = v.y;
            wv[j * 4 + 2] = v.z; wv[j * 4 + 3] = v.w;
        }
        float* kb = kvbuf + (size_t)b * 2 * NM * ND;
#pragma unroll
        for (int m = 0; m < NM; ++m) {
            float aK = 0.f, aV = 0.f;
#pragma unroll
            for (int r = 0; r < NR; ++r) {
                float mv = sM16[m * NR + r];
                aK += mv * wk[r];
                aV += mv * wv[r];
            }
            kb[m * ND + t]           = aK * 0.25f;   // fold 1/sqrt(R)
            kb[NM * ND + m * ND + t] = aV;
        }
    }
}

// ---------------------------------------------------------------------------
// Kernel 1: read path. scores = q·K^T, softmax, out = attn·V.
// Fused: partial column-sums of `interface` -> ipart.
// grid = (NCB, NB), block = 256. 8 lanes per group, 4 tokens per group.
// No occupancy cap: sc[4][16] needs ~100 live VGPRs (spilled at 64 in R4).
// ---------------------------------------------------------------------------
__global__ __launch_bounds__(256) void ulm_read_kernel(
    const float* __restrict__ query,
    const float* __restrict__ iface,
    const float* __restrict__ kvbuf,   // [NB][2][NM][ND]
    float* __restrict__ read_out,      // [NB][NS][ND]
    float* __restrict__ ipart)         // [NB][NCB][ND]
{
    __shared__ __align__(16) float sKV[2 * NM * ND];  // 20 KB: K then V
    __shared__ float4 sIred[4 * ND4];                 // 2.5 KB

    const int t = threadIdx.x;
    const int chunk = blockIdx.x;
    const int b = blockIdx.y;
    const int s0 = chunk * TPB;

    // --- stage folded K,V (coalesced, conflict-free) ------------------------
    {
        const float4* kv4 = reinterpret_cast<const float4*>(kvbuf + (size_t)b * 2 * NM * ND);
        float4* s4 = reinterpret_cast<float4*>(sKV);
#pragma unroll
        for (int j = 0; j < 5; ++j) s4[j * 256 + t] = kv4[j * 256 + t];
    }
    __syncthreads();

    const float4* sK4 = reinterpret_cast<const float4*>(sKV);
    const float4* sV4 = sK4 + NM * ND4;

    const int l = t & 7;                  // lane in 8-lane group
    const int G = t >> 3;                 // group 0..31
    const int tokb = G * 4;               // 4 tokens per group

    const float4* q4 = reinterpret_cast<const float4*>(query + ((size_t)b * NS + s0) * ND);

    // --- scores: 16 dots of length 160 per token, 8-lane distributed -------
    float sc[4][NM];
#pragma unroll
    for (int i = 0; i < 4; ++i)
#pragma unroll
        for (int m = 0; m < NM; ++m) sc[i][m] = 0.f;

#pragma unroll
    for (int k = 0; k < 5; ++k) {
        float4 qa[4];
#pragma unroll
        for (int i = 0; i < 4; ++i) qa[i] = q4[(tokb + i) * ND4 + l + 8 * k];
#pragma unroll
        for (int m = 0; m < NM; ++m) {
            float4 kv = sK4[m * ND4 + l + 8 * k];
#pragma unroll
            for (int i = 0; i < 4; ++i)
                sc[i][m] += qa[i].x * kv.x + qa[i].y * kv.y
                          + qa[i].z * kv.z + qa[i].w * kv.w;
        }
    }
#pragma unroll
    for (int i = 0; i < 4; ++i)
#pragma unroll
        for (int m = 0; m < NM; ++m) {
            float v = sc[i][m];
            v += __shfl_xor(v, 1);
            v += __shfl_xor(v, 2);
            v += __shfl_xor(v, 4);
            sc[i][m] = v;
        }

    // --- softmax (redundant per lane) ---------------------------------------
#pragma unroll
    for (int i = 0; i < 4; ++i) {
        float mx = -1e30f;
#pragma unroll
        for (int m = 0; m < NM; ++m) mx = fmaxf(mx, sc[i][m]);
        float sm = 0.f;
#pragma unroll
        for (int m = 0; m < NM; ++m) { float e = __expf(sc[i][m] - mx); sc[i][m] = e; sm += e; }
        float inv = 1.f / sm;
#pragma unroll
        for (int m = 0; m < NM; ++m) sc[i][m] *= inv;
    }

    // --- out = attn · V (nontemporal stores: output is never re-read) ------
    float4* out4 = reinterpret_cast<float4*>(read_out + ((size_t)b * NS + s0) * ND);
#pragma unroll
    for (int k = 0; k < 5; ++k) {
        float4 o[4];
#pragma unroll
        for (int i = 0; i < 4; ++i) o[i] = make_float4(0.f, 0.f, 0.f, 0.f);
#pragma unroll
        for (int m = 0; m < NM; ++m) {
            float4 vv = sV4[m * ND4 + l + 8 * k];
#pragma unroll
            for (int i = 0; i < 4; ++i) {
                o[i].x += sc[i][m] * vv.x; o[i].y += sc[i][m] * vv.y;
                o[i].z += sc[i][m] * vv.z; o[i].w += sc[i][m] * vv.w;
            }
        }
#pragma unroll
        for (int i = 0; i < 4; ++i) {
            f32x4 ov; ov.x = o[i].x; ov.y = o[i].y; ov.z = o[i].z; ov.w = o[i].w;
            __builtin_nontemporal_store(ov,
                reinterpret_cast<f32x4*>(out4 + (tokb + i) * ND4 + l + 8 * k));
        }
    }

    // --- iface column-sums: per-k load+butterfly, nothing hoarded ----------
    const float4* i4 = reinterpret_cast<const float4*>(iface + ((size_t)b * NS + s0) * ND);
    const int w = t >> 6;
#pragma unroll
    for (int k = 0; k < 5; ++k) {
        float x = 0.f, y = 0.f, z = 0.f, u = 0.f;
#pragma unroll
        for (int i = 0; i < 4; ++i) {
            float4 v = i4[(tokb + i) * ND4 + l + 8 * k];
            x += v.x; y += v.y; z += v.z; u += v.w;
        }
#pragma unroll
        for (int off = 8; off <= 32; off <<= 1) {
            x += __shfl_xor(x, off); y += __shfl_xor(y, off);
            z += __shfl_xor(z, off); u += __shfl_xor(u, off);
        }
        if ((t & 63) < 8) sIred[w * ND4 + k * 8 + l] = make_float4(x, y, z, u);
    }
    __syncthreads();
    if (t < ND4) {
        float4 a0 = sIred[t], a1 = sIred[ND4 + t];
        float4 a2 = sIred[2 * ND4 + t], a3 = sIred[3 * ND4 + t];
        float4 tot = make_float4(a0.x + a1.x + a2.x + a3.x,
                                 a0.y + a1.y + a2.y + a3.y,
                                 a0.z + a1.z + a2.z + a3.z,
                                 a0.w + a1.w + a2.w + a3.w);
        reinterpret_cast<float4*>(ipart + ((size_t)(b * NCB + chunk)) * ND)[t] = tot;
    }
}

// ---------------------------------------------------------------------------
// Kernel 2: write path. i_mean -> i_proj -> erase/add -> layer_norm(new_mem)
// grid = NB, block = 256
// ---------------------------------------------------------------------------
__global__ __launch_bounds__(256) void ulm_write_kernel(
    const float* __restrict__ memory,
    const float* __restrict__ Wwk,     // [NR][ND]
    const float* __restrict__ Wwe,     // [ND][NR]
    const float* __restrict__ Wwa,     // [ND][NR]
    const float* __restrict__ ipart,   // [NB][NCB][ND]
    float* __restrict__ new_mem)       // [NB][NM][ND]
{
    __shared__ float sIm[ND];
    __shared__ float sIp[NR];
    __shared__ float sOmE[ND];   // 1 - erase
    __shared__ float sAdd[ND];

    const int b = blockIdx.x;
    const int t = threadIdx.x;

    if (t < ND) {
        float acc = 0.f;
#pragma unroll 8
        for (int c = 0; c < NCB; ++c)
            acc += ipart[((size_t)(b * NCB + c)) * ND + t];
        sIm[t] = acc * (1.0f / NS);
    }
    __syncthreads();

    if (t < NR) {
        float acc = 0.f;
        for (int d = 0; d < ND; ++d) acc += sIm[d] * Wwk[t * ND + d];
        sIp[t] = acc;
    }
    __syncthreads();

    if (t < ND) {
        float e = 0.f, a = 0.f;
#pragma unroll
        for (int r = 0; r < NR; ++r) {
            float ip = sIp[r];
            e += ip * Wwe[t * NR + r];
            a += ip * Wwa[t * NR + r];
        }
        sOmE[t] = 1.0f - 1.0f / (1.0f + __expf(-e));
        sAdd[t] = a;
    }
    __syncthreads();

    // layer norm each of the 16 memory rows; one wave per row
    const int wave = t >> 6, lane = t & 63;
    for (int m = wave; m < NM; m += 4) {
        const float* mrow = memory + ((size_t)b * NM + m) * ND;
        float v0 = mrow[lane] * sOmE[lane] + sAdd[lane];
        float v1 = mrow[lane + 64] * sOmE[lane + 64] + sAdd[lane + 64];
        float v2 = 0.f;
        const bool has2 = lane < 32;
        if (has2) v2 = mrow[lane + 128] * sOmE[lane + 128] + sAdd[lane + 128];
        float s  = v0 + v1 + v2;
        float sq = v0 * v0 + v1 * v1 + v2 * v2;
#pragma unroll
        for (int off = 32; off; off >>= 1) {
            s  += __shfl_xor(s, off);
            sq += __shfl_xor(sq, off);
        }
        float mu   = s * (1.0f / ND);
        float var  = sq * (1.0f / ND) - mu * mu;
        float rstd = rsqrtf(var + 1e-5f);
        float* orow = new_mem + ((size_t)b * NM + m) * ND;
        orow[lane]      = (v0 - mu) * rstd;
        orow[lane + 64] = (v1 - mu) * rstd;
        if (has2) orow[lane + 128] = (v2 - mu) * rstd;
    }
}

extern "C" void kernel_launch(void* const* d_in, const int* in_sizes, int n_in,
                              void* d_out, int out_size, void* d_ws, size_t ws_size,
                              hipStream_t stream) {
    const float* query  = (const float*)d_in[0];
    const float* iface  = (const float*)d_in[1];
    const float* memory = (const float*)d_in[2];
    const float* Wrk    = (const float*)d_in[3];
    const float* Wrv    = (const float*)d_in[4];
    const float* Wwk    = (const float*)d_in[5];
    const float* Wwe    = (const float*)d_in[6];
    const float* Wwa    = (const float*)d_in[7];

    float* read_out = (float*)d_out;                        // [32][4096][160]
    float* new_mem  = (float*)d_out + (size_t)NB * NS * ND; // [32][16][160]
    float* ipart    = (float*)d_ws;                         // NB*NCB*ND f32
    float* kvbuf    = (float*)d_ws + (size_t)NB * NCB * ND; // NB*2*NM*ND f32

    ulm_fold_kv<<<NB, 256, 0, stream>>>(memory, Wrk, Wrv, kvbuf);
    dim3 grid1(NCB, NB);
    ulm_read_kernel<<<grid1, 256, 0, stream>>>(query, iface, kvbuf,
                                               read_out, ipart);
    ulm_write_kernel<<<NB, 256, 0, stream>>>(memory, Wwk, Wwe, Wwa, ipart, new_mem);
}